// Round 1
// baseline (1898.540 us; speedup 1.0000x reference)
//
#include <hip/hip_runtime.h>

constexpr int DE   = 128;
constexpr int DRBF = 16;
constexpr int TILE = 64;     // atoms per block in atom kernel
constexpr int APAD = 140;    // padded row (floats); 140*4=560 bytes, 16B-aligned, bank-friendly

#define INV_SCALE_SILU (1.0f / 0.6f)
#define INV_SQRT2 0.70710678118654752f

__device__ __forceinline__ float ssilu(float x) {
    return x * (1.0f / (1.0f + __expf(-x))) * INV_SCALE_SILU;
}

// ---------------------------------------------------------------------------
// Edge kernel: x[e][c] = m[e][c] * (rbf[e] . W_rbf[c]) ; atomicAdd into acc[id_j[e]][c]
// One wave per edge; lane owns cols 2*lane, 2*lane+1. W_rbf rows live in registers
// (per-lane constant across all edges).
// ---------------------------------------------------------------------------
__global__ __launch_bounds__(256) void edge_kernel(
    const float* __restrict__ m, const float* __restrict__ rbf,
    const int* __restrict__ id_j, const float* __restrict__ W_rbf,
    float* __restrict__ acc, int E)
{
    const int lane = threadIdx.x & 63;
    const int wid  = blockIdx.x * (blockDim.x >> 6) + (threadIdx.x >> 6);
    const int nw   = gridDim.x * (blockDim.x >> 6);
    const int c0   = lane * 2;

    float w0[DRBF], w1[DRBF];
#pragma unroll
    for (int k = 0; k < DRBF; ++k) {
        w0[k] = W_rbf[(size_t)c0 * DRBF + k];
        w1[k] = W_rbf[(size_t)(c0 + 1) * DRBF + k];
    }

    for (int e = wid; e < E; e += nw) {
        const float4* r4 = reinterpret_cast<const float4*>(rbf + (size_t)e * DRBF);
        float4 ra = r4[0], rb = r4[1], rc = r4[2], rd = r4[3];
        float r[16] = {ra.x, ra.y, ra.z, ra.w, rb.x, rb.y, rb.z, rb.w,
                       rc.x, rc.y, rc.z, rc.w, rd.x, rd.y, rd.z, rd.w};
        float a0 = 0.f, a1 = 0.f;
#pragma unroll
        for (int k = 0; k < DRBF; ++k) { a0 += w0[k] * r[k]; a1 += w1[k] * r[k]; }

        float2 mv = reinterpret_cast<const float2*>(m + (size_t)e * DE)[lane];
        int id = id_j[e];
        float* dst = acc + (size_t)id * DE + c0;
        atomicAdd(dst + 0, mv.x * a0);
        atomicAdd(dst + 1, mv.y * a1);
    }
}

// ---------------------------------------------------------------------------
// Atom kernel: in-place MLP on the scattered accumulator (d_out).
// Per block: TILE=64 atom rows. LDS: A[64][140], B[64][140], W[128][128] (XOR-swizzled).
// Thread t: atoms (t>>4)*4 .. +3, cols (t&15)*8 .. +7  (4x8 register tile).
// ---------------------------------------------------------------------------
__device__ __forceinline__ void load_w(float* __restrict__ Wl,
                                       const float* __restrict__ Wg, int t)
{
    const float4* g4 = reinterpret_cast<const float4*>(Wg);
    float4* l4 = reinterpret_cast<float4*>(Wl);
#pragma unroll
    for (int r = 0; r < 16; ++r) {
        int idx4 = t + 256 * r;          // float4 index in [0,4096)
        int c  = idx4 >> 5;              // 32 float4 per row of 128
        int k4 = idx4 & 31;
        float4 v = g4[idx4];
        l4[c * 32 + (k4 ^ ((c >> 3) & 7))] = v;   // XOR swizzle keyed on c>>3
    }
}

template <bool RES>
__device__ __forceinline__ void gemm_tile(const float* __restrict__ In,
                                          float* __restrict__ Out,
                                          const float* __restrict__ Wl, int t)
{
    const int ag = t >> 4;      // 16 groups * 4 atoms
    const int cg = t & 15;      // 16 groups * 8 cols
    const int sw = cg & 7;
    float acc[4][8];
#pragma unroll
    for (int i = 0; i < 4; ++i)
#pragma unroll
        for (int j = 0; j < 8; ++j) acc[i][j] = 0.f;

    const float4* In4 = reinterpret_cast<const float4*>(In);
    const float4* W4  = reinterpret_cast<const float4*>(Wl);

#pragma unroll 4
    for (int k4 = 0; k4 < 32; ++k4) {
        float4 av[4];
#pragma unroll
        for (int i = 0; i < 4; ++i)
            av[i] = In4[(ag * 4 + i) * (APAD / 4) + k4];
        float4 wv[8];
#pragma unroll
        for (int j = 0; j < 8; ++j)
            wv[j] = W4[(cg * 8 + j) * 32 + (k4 ^ sw)];
#pragma unroll
        for (int i = 0; i < 4; ++i)
#pragma unroll
            for (int j = 0; j < 8; ++j)
                acc[i][j] += av[i].x * wv[j].x + av[i].y * wv[j].y
                           + av[i].z * wv[j].z + av[i].w * wv[j].w;
    }

#pragma unroll
    for (int i = 0; i < 4; ++i) {
        int a = ag * 4 + i;
#pragma unroll
        for (int j = 0; j < 8; ++j) {
            int c = cg * 8 + j;
            float h = ssilu(acc[i][j]);
            if (RES) Out[a * APAD + c] = (Out[a * APAD + c] + h) * INV_SQRT2;
            else     Out[a * APAD + c] = h;
        }
    }
}

__global__ __launch_bounds__(256) void atom_kernel(
    float* __restrict__ out,          // [nAtoms][128], holds scatter acc; in-place
    const float* __restrict__ W1, const float* __restrict__ W_res,
    const float* __restrict__ scale_p, int nAtoms)
{
    extern __shared__ float smem[];
    float* A = smem;                       // [64][140]
    float* B = smem + TILE * APAD;         // [64][140]
    float* W = smem + 2 * TILE * APAD;     // [128][128] swizzled

    const int t = threadIdx.x;
    const int tile0 = blockIdx.x * TILE;
    const float scale = scale_p[0];

    // Load atom tile (x2 * scale) -> A
    const float4* g4 = reinterpret_cast<const float4*>(out + (size_t)tile0 * DE);
#pragma unroll
    for (int r = 0; r < 8; ++r) {
        int idx4 = t + 256 * r;            // [0, 64*32)
        int a = idx4 >> 5, k4 = idx4 & 31;
        float4 v = make_float4(0.f, 0.f, 0.f, 0.f);
        if (tile0 + a < nAtoms) v = g4[idx4];
        v.x *= scale; v.y *= scale; v.z *= scale; v.w *= scale;
        reinterpret_cast<float4*>(A + a * APAD)[k4] = v;
    }

    __syncthreads();
    load_w(W, W1, t);
    __syncthreads();
    gemm_tile<false>(A, B, W, t);          // B = ssilu(A @ W1^T)

    __syncthreads();
    load_w(W, W_res + 0 * 16384, t);
    __syncthreads();
    gemm_tile<false>(B, A, W, t);          // A = t = ssilu(B @ W00^T)

    __syncthreads();
    load_w(W, W_res + 1 * 16384, t);
    __syncthreads();
    gemm_tile<true>(A, B, W, t);           // B = (B + ssilu(A @ W01^T)) * inv_sqrt2

    __syncthreads();
    load_w(W, W_res + 2 * 16384, t);
    __syncthreads();
    gemm_tile<false>(B, A, W, t);          // A = ssilu(B @ W10^T)

    __syncthreads();
    load_w(W, W_res + 3 * 16384, t);
    __syncthreads();
    gemm_tile<true>(A, B, W, t);           // B = (B + ssilu(A @ W11^T)) * inv_sqrt2

    __syncthreads();
#pragma unroll
    for (int r = 0; r < 8; ++r) {
        int idx4 = t + 256 * r;
        int a = idx4 >> 5, k4 = idx4 & 31;
        if (tile0 + a < nAtoms) {
            float4 v = reinterpret_cast<const float4*>(B + a * APAD)[k4];
            reinterpret_cast<float4*>(out + (size_t)tile0 * DE)[idx4] = v;
        }
    }
}

// ---------------------------------------------------------------------------
extern "C" void kernel_launch(void* const* d_in, const int* in_sizes, int n_in,
                              void* d_out, int out_size, void* d_ws, size_t ws_size,
                              hipStream_t stream)
{
    (void)d_ws; (void)ws_size; (void)n_in;
    // dict order: nAtoms, m, rbf, id_j, W_rbf, scale, W1, W_res
    const float* m      = (const float*)d_in[1];
    const float* rbf    = (const float*)d_in[2];
    const int*   id_j   = (const int*)d_in[3];
    const float* W_rbf  = (const float*)d_in[4];
    const float* scale  = (const float*)d_in[5];
    const float* W1     = (const float*)d_in[6];
    const float* W_res  = (const float*)d_in[7];
    float* out = (float*)d_out;

    const int E      = in_sizes[3];
    const int nAtoms = out_size / DE;

    // Accumulator = d_out; zero it (harness poisons with 0xAA before each call)
    hipMemsetAsync(out, 0, (size_t)out_size * sizeof(float), stream);

    edge_kernel<<<2048, 256, 0, stream>>>(m, rbf, id_j, W_rbf, out, E);

    const int lds_bytes = (2 * TILE * APAD + 128 * 128) * (int)sizeof(float); // 137216
    static_assert((2 * TILE * APAD + 128 * 128) * sizeof(float) <= 160 * 1024, "LDS overflow");
    hipFuncSetAttribute(reinterpret_cast<const void*>(atom_kernel),
                        hipFuncAttributeMaxDynamicSharedMemorySize, lds_bytes);
    int blocks = (nAtoms + TILE - 1) / TILE;
    atom_kernel<<<blocks, 256, lds_bytes, stream>>>(out, W1, W_res, scale, nAtoms);
}